// Round 4
// baseline (1948.214 us; speedup 1.0000x reference)
//
#include <hip/hip_runtime.h>
#include <hip/hip_bf16.h>
#include <stdint.h>

// ---------------------------------------------------------------------------
// DeepseekV2 decoder layer, bf16 MFMA path, round 4.
// R3 post-mortem: GEMMs at the m97 2-barrier plateau (MfmaUtil 36.5%,
// HBM 14% - not memory bound). This round: AITER-style K-loop -
// buffer_load->VGPR->ds_write staging (2-iter lookahead, 2 reg slots),
// double-buffered LDS, ONE raw s_barrier per K-step with lgkm-only drain
// so global loads stay in flight across the barrier.
// ---------------------------------------------------------------------------

typedef __bf16 bf16;
typedef bf16 bf16x8 __attribute__((ext_vector_type(8)));
typedef bf16 bf16x4 __attribute__((ext_vector_type(4)));
typedef float f32x4 __attribute__((ext_vector_type(4)));

#define HID     2048
#define TOK     4096
#define INTER   10944
#define INTER_P 11008   // padded to multiple of 128; pad region is zeros
#define BK      32

// lgkm-only drain + barrier: does NOT wait vmcnt, so in-flight global->VGPR
// loads (private dests, read-only sources) cross the barrier legally.
__device__ __forceinline__ void barrier_lgkm() {
    __asm__ volatile("s_waitcnt lgkmcnt(0)" ::: "memory");
    __builtin_amdgcn_s_barrier();
}

// ---------------------------------------------------------------------------
// fp32 -> bf16 conversion with zero tail (row padding for Wg/Wu).
// ---------------------------------------------------------------------------
__global__ __launch_bounds__(256) void conv_pad(const float* __restrict__ src,
                                                bf16* __restrict__ dst,
                                                int n_src, int n_dst) {
    int i = (blockIdx.x * 256 + threadIdx.x) * 4;
    if (i >= n_dst) return;
    float4 v = make_float4(0.f, 0.f, 0.f, 0.f);
    if (i < n_src) v = *(const float4*)(src + i);
    bf16x4 o;
    o[0] = (bf16)v.x; o[1] = (bf16)v.y; o[2] = (bf16)v.z; o[3] = (bf16)v.w;
    *(bf16x4*)(dst + i) = o;
}

// Wd [2048,10944] -> [2048,11008], columns padded with zeros.
__global__ __launch_bounds__(256) void conv_wd(const float* __restrict__ src,
                                               bf16* __restrict__ dst) {
    int i = (blockIdx.x * 256 + threadIdx.x) * 4;
    if (i >= HID * INTER_P) return;
    int row = i / INTER_P;
    int col = i - row * INTER_P;
    float4 v = make_float4(0.f, 0.f, 0.f, 0.f);
    if (col < INTER)
        v = *(const float4*)(src + (size_t)row * INTER + col);
    bf16x4 o;
    o[0] = (bf16)v.x; o[1] = (bf16)v.y; o[2] = (bf16)v.z; o[3] = (bf16)v.w;
    *(bf16x4*)(dst + i) = o;
}

// ---------------------------------------------------------------------------
// RMSNorm: one block per row of 2048 fp32, emit bf16 * w.
// ---------------------------------------------------------------------------
__global__ __launch_bounds__(256) void rmsnorm_k(const float* __restrict__ x,
                                                 const float* __restrict__ w,
                                                 bf16* __restrict__ out) {
    const int row = blockIdx.x;
    const int tid = threadIdx.x;
    const float* xr = x + (size_t)row * HID + tid * 8;
    float4 v0 = *(const float4*)(xr);
    float4 v1 = *(const float4*)(xr + 4);
    float s = v0.x * v0.x + v0.y * v0.y + v0.z * v0.z + v0.w * v0.w +
              v1.x * v1.x + v1.y * v1.y + v1.z * v1.z + v1.w * v1.w;
    #pragma unroll
    for (int o = 32; o > 0; o >>= 1) s += __shfl_down(s, o);
    __shared__ float red[4];
    if ((tid & 63) == 0) red[tid >> 6] = s;
    __syncthreads();
    float tot = red[0] + red[1] + red[2] + red[3];
    float scale = rsqrtf(tot * (1.0f / (float)HID) + 1e-6f);
    float4 w0 = *(const float4*)(w + tid * 8);
    float4 w1 = *(const float4*)(w + tid * 8 + 4);
    bf16x8 o8;
    o8[0] = (bf16)(v0.x * scale * w0.x);
    o8[1] = (bf16)(v0.y * scale * w0.y);
    o8[2] = (bf16)(v0.z * scale * w0.z);
    o8[3] = (bf16)(v0.w * scale * w0.w);
    o8[4] = (bf16)(v1.x * scale * w1.x);
    o8[5] = (bf16)(v1.y * scale * w1.y);
    o8[6] = (bf16)(v1.z * scale * w1.z);
    o8[7] = (bf16)(v1.w * scale * w1.w);
    *(bf16x8*)(out + (size_t)row * HID + tid * 8) = o8;
}

// ---------------------------------------------------------------------------
// Pipelined GEMM C[M,N] = A[M,K] * W[N,K]^T. 512 thr, 128x128 tile, BK=32,
// wave = 64x32 (2x4 wave grid). VGPR staging, 2-iter lookahead, LDS dbuf,
// one lgkm-only barrier per K-step. grid: x = M-tile (fastest), y = N-panel.
// EPI=0: bf16 store. EPI=1: fp32 res[idx]+acc store.
// ---------------------------------------------------------------------------
template <int EPI>
__global__ __launch_bounds__(512, 4) void gemm_bt5(const bf16* __restrict__ A,
                                                   const bf16* __restrict__ W,
                                                   const float* __restrict__ res,
                                                   void* __restrict__ out,
                                                   int N, int K) {
    __shared__ bf16 lA[2][128 * BK];
    __shared__ bf16 lW[2][128 * BK];
    const int tid = threadIdx.x;
    const int rowBase = blockIdx.x * 128;
    const int colBase = blockIdx.y * 128;
    const int wave = tid >> 6, lane = tid & 63;
    const int wm = (wave >> 2) * 64, wn = (wave & 3) * 32;
    const int lr = lane & 15, kq = lane >> 4;

    f32x4 acc[4][2] = {};

    // staging: thread = chunk; swizzled global source (r=tid>>2, s^=(r>>1)&3)
    const int sr = tid >> 2;
    const int ss = (tid & 3) ^ ((sr >> 1) & 3);
    const bf16* Ag = A + (size_t)rowBase * K + (size_t)sr * K + ss * 8;
    const bf16* Wg = W + (size_t)colBase * K + (size_t)sr * K + ss * 8;
    bf16* ldA = &lA[0][0] + tid * 8;   // chunk base in buf0; buf1 = +128*BK
    bf16* ldW = &lW[0][0] + tid * 8;

    // frag read offsets (swizzle-matched)
    int aoff[4], woff[2];
    #pragma unroll
    for (int i = 0; i < 4; ++i) {
        int r = wm + i * 16 + lr;
        aoff[i] = r * BK + (kq ^ ((r >> 1) & 3)) * 8;
    }
    #pragma unroll
    for (int i = 0; i < 2; ++i) {
        int r = wn + i * 16 + lr;
        woff[i] = r * BK + (kq ^ ((r >> 1) & 3)) * 8;
    }

    const int nk = K / BK;  // even (64 or 344)
    uint4 sA[2], sW[2];
    // prologue: tile0 -> slot0 -> buf0; tile1 -> slot1 (left in flight)
    sA[0] = *(const uint4*)(Ag);
    sW[0] = *(const uint4*)(Wg);
    sA[1] = *(const uint4*)(Ag + BK);
    sW[1] = *(const uint4*)(Wg + BK);
    *(uint4*)ldA = sA[0];
    *(uint4*)ldW = sW[0];
    barrier_lgkm();

    for (int j0 = 0; j0 < nk; j0 += 2) {
        #pragma unroll
        for (int h = 0; h < 2; ++h) {
            const int j = j0 + h;
            // issue loads for tile j+2 into slot[h]
            const int k2 = (j + 2 < nk) ? (j + 2) * BK : 0;
            sA[h] = *(const uint4*)(Ag + k2);
            sW[h] = *(const uint4*)(Wg + k2);
            // compute tile j from buf[h]
            const int cb = h * 128 * BK;
            bf16x8 af[4], wf[2];
            #pragma unroll
            for (int i = 0; i < 4; ++i)
                af[i] = *(const bf16x8*)&lA[0][cb + aoff[i]];
            #pragma unroll
            for (int i = 0; i < 2; ++i)
                wf[i] = *(const bf16x8*)&lW[0][cb + woff[i]];
            #pragma unroll
            for (int mi = 0; mi < 4; ++mi)
                #pragma unroll
                for (int ni = 0; ni < 2; ++ni)
                    acc[mi][ni] = __builtin_amdgcn_mfma_f32_16x16x32_bf16(
                        af[mi], wf[ni], acc[mi][ni], 0, 0, 0);
            // write tile j+1 (slot[h^1], loaded 2 iters ago) into buf[h^1]
            const int nb = (h ^ 1) * 128 * BK * (int)sizeof(bf16);
            *(uint4*)((char*)ldA + nb) = sA[h ^ 1];
            *(uint4*)((char*)ldW + nb) = sW[h ^ 1];
            barrier_lgkm();
        }
    }
    // C/D layout: col = lane&15, row = (lane>>4)*4 + reg  [m89/m91]
    const int rq = lane >> 4, cn = lane & 15;
    #pragma unroll
    for (int mi = 0; mi < 4; ++mi) {
        #pragma unroll
        for (int ni = 0; ni < 2; ++ni) {
            int col = colBase + wn + ni * 16 + cn;
            #pragma unroll
            for (int r = 0; r < 4; ++r) {
                int row = rowBase + wm + mi * 16 + rq * 4 + r;
                size_t idx = (size_t)row * N + col;
                float v = acc[mi][ni][r];
                if (EPI == 0) ((bf16*)out)[idx] = (bf16)v;
                else          ((float*)out)[idx] = res[idx] + v;
            }
        }
    }
}

// ---------------------------------------------------------------------------
// Pipelined fused gate/up, same structure, 3 staged streams (A, Wg, Wu).
// ---------------------------------------------------------------------------
__global__ __launch_bounds__(512, 3) void gemm_gu5(const bf16* __restrict__ A,
                                                   const bf16* __restrict__ Wgp,
                                                   const bf16* __restrict__ Wup,
                                                   bf16* __restrict__ out,
                                                   int N, int K) {
    __shared__ bf16 lA[2][128 * BK];
    __shared__ bf16 lG[2][128 * BK];
    __shared__ bf16 lU[2][128 * BK];
    const int tid = threadIdx.x;
    const int rowBase = blockIdx.x * 128;
    const int colBase = blockIdx.y * 128;
    const int wave = tid >> 6, lane = tid & 63;
    const int wm = (wave >> 2) * 64, wn = (wave & 3) * 32;
    const int lr = lane & 15, kq = lane >> 4;

    f32x4 ag[4][2] = {};
    f32x4 au[4][2] = {};

    const int sr = tid >> 2;
    const int ss = (tid & 3) ^ ((sr >> 1) & 3);
    const bf16* Ag = A   + (size_t)rowBase * K + (size_t)sr * K + ss * 8;
    const bf16* Gg = Wgp + (size_t)colBase * K + (size_t)sr * K + ss * 8;
    const bf16* Ug = Wup + (size_t)colBase * K + (size_t)sr * K + ss * 8;
    bf16* ldA = &lA[0][0] + tid * 8;
    bf16* ldG = &lG[0][0] + tid * 8;
    bf16* ldU = &lU[0][0] + tid * 8;

    int aoff[4], boff[2];
    #pragma unroll
    for (int i = 0; i < 4; ++i) {
        int r = wm + i * 16 + lr;
        aoff[i] = r * BK + (kq ^ ((r >> 1) & 3)) * 8;
    }
    #pragma unroll
    for (int i = 0; i < 2; ++i) {
        int r = wn + i * 16 + lr;
        boff[i] = r * BK + (kq ^ ((r >> 1) & 3)) * 8;
    }

    const int nk = K / BK;
    uint4 sA[2], sG[2], sU[2];
    sA[0] = *(const uint4*)(Ag);
    sG[0] = *(const uint4*)(Gg);
    sU[0] = *(const uint4*)(Ug);
    sA[1] = *(const uint4*)(Ag + BK);
    sG[1] = *(const uint4*)(Gg + BK);
    sU[1] = *(const uint4*)(Ug + BK);
    *(uint4*)ldA = sA[0];
    *(uint4*)ldG = sG[0];
    *(uint4*)ldU = sU[0];
    barrier_lgkm();

    for (int j0 = 0; j0 < nk; j0 += 2) {
        #pragma unroll
        for (int h = 0; h < 2; ++h) {
            const int j = j0 + h;
            const int k2 = (j + 2 < nk) ? (j + 2) * BK : 0;
            sA[h] = *(const uint4*)(Ag + k2);
            sG[h] = *(const uint4*)(Gg + k2);
            sU[h] = *(const uint4*)(Ug + k2);
            const int cb = h * 128 * BK;
            bf16x8 af[4], gf[2], uf[2];
            #pragma unroll
            for (int i = 0; i < 4; ++i)
                af[i] = *(const bf16x8*)&lA[0][cb + aoff[i]];
            #pragma unroll
            for (int i = 0; i < 2; ++i) {
                gf[i] = *(const bf16x8*)&lG[0][cb + boff[i]];
                uf[i] = *(const bf16x8*)&lU[0][cb + boff[i]];
            }
            #pragma unroll
            for (int mi = 0; mi < 4; ++mi)
                #pragma unroll
                for (int ni = 0; ni < 2; ++ni) {
                    ag[mi][ni] = __builtin_amdgcn_mfma_f32_16x16x32_bf16(
                        af[mi], gf[ni], ag[mi][ni], 0, 0, 0);
                    au[mi][ni] = __builtin_amdgcn_mfma_f32_16x16x32_bf16(
                        af[mi], uf[ni], au[mi][ni], 0, 0, 0);
                }
            const int nb = (h ^ 1) * 128 * BK * (int)sizeof(bf16);
            *(uint4*)((char*)ldA + nb) = sA[h ^ 1];
            *(uint4*)((char*)ldG + nb) = sG[h ^ 1];
            *(uint4*)((char*)ldU + nb) = sU[h ^ 1];
            barrier_lgkm();
        }
    }
    const int rq = lane >> 4, cn = lane & 15;
    #pragma unroll
    for (int mi = 0; mi < 4; ++mi) {
        #pragma unroll
        for (int ni = 0; ni < 2; ++ni) {
            int col = colBase + wn + ni * 16 + cn;
            #pragma unroll
            for (int r = 0; r < 4; ++r) {
                int row = rowBase + wm + mi * 16 + rq * 4 + r;
                float g = ag[mi][ni][r];
                float u = au[mi][ni][r];
                float sg = g / (1.0f + __expf(-g));  // silu
                out[(size_t)row * N + col] = (bf16)(sg * u);
            }
        }
    }
}

// ---------------------------------------------------------------------------
extern "C" void kernel_launch(void* const* d_in, const int* in_sizes, int n_in,
                              void* d_out, int out_size, void* d_ws, size_t ws_size,
                              hipStream_t stream) {
    const float* x      = (const float*)d_in[0];
    const float* in_w   = (const float*)d_in[2];
    const float* post_w = (const float*)d_in[3];
    const float* Wq     = (const float*)d_in[4];
    const float* Wo     = (const float*)d_in[5];
    const float* Wg     = (const float*)d_in[6];
    const float* Wu     = (const float*)d_in[7];
    const float* Wd     = (const float*)d_in[8];

    char* ws = (char*)d_ws;
    bf16*  X    = (bf16*)(ws + 0);           // 16.8MB: h_norm, later h_post
    bf16*  Yq   = (bf16*)(ws + 16777216);    // 16.8MB: q (bf16)
    float* hid  = (float*)(ws + 33554432);   // 33.6MB: hidden (fp32 residual)
    bf16*  gu   = (bf16*)(ws + 67108864);    // 90.2MB: silu(g)*u, padded
    bf16*  w0   = (bf16*)(ws + 157286400);   // 45.1MB: Wg bf16, later Wd bf16
    bf16*  w1   = (bf16*)(ws + 202375168);   // 45.1MB: Wu bf16
    bf16*  wsm  = (bf16*)(ws + 247463936);   // 8.4MB : Wq bf16, later Wo bf16

    const int nGU  = INTER_P * HID;
    const int nGUs = INTER * HID;
    const int nSq  = HID * HID;

    conv_pad<<<nGU / 4 / 256, 256, 0, stream>>>(Wg, w0, nGUs, nGU);
    conv_pad<<<nGU / 4 / 256, 256, 0, stream>>>(Wu, w1, nGUs, nGU);
    conv_pad<<<nSq / 4 / 256, 256, 0, stream>>>(Wq, wsm, nSq, nSq);

    rmsnorm_k<<<TOK, 256, 0, stream>>>(x, in_w, X);
    // q = h_norm @ Wq^T
    gemm_bt5<0><<<dim3(TOK / 128, HID / 128), 512, 0, stream>>>(
        X, wsm, nullptr, Yq, HID, HID);
    conv_pad<<<nSq / 4 / 256, 256, 0, stream>>>(Wo, wsm, nSq, nSq);
    // hidden = x + q @ Wo^T
    gemm_bt5<1><<<dim3(TOK / 128, HID / 128), 512, 0, stream>>>(
        Yq, wsm, x, hid, HID, HID);
    rmsnorm_k<<<TOK, 256, 0, stream>>>(hid, post_w, X);
    // gu = silu(h_post @ Wg^T) * (h_post @ Wu^T)
    gemm_gu5<<<dim3(TOK / 128, INTER_P / 128), 512, 0, stream>>>(
        X, w0, w1, gu, INTER_P, HID);
    conv_wd<<<nGU / 4 / 256, 256, 0, stream>>>(Wd, w0);
    // out = hidden + gu @ Wd^T
    gemm_bt5<1><<<dim3(TOK / 128, HID / 128), 512, 0, stream>>>(
        gu, w0, hid, (float*)d_out, HID, INTER_P);
}